// Round 2
// baseline (59.499 us; speedup 1.0000x reference)
//
#include <hip/hip_runtime.h>

#define BB 4
#define RR 160
#define HH 128
#define WW 128
#define CC 64
#define NREG 32
#define PH 7
#define PW 7
#define NTHREADS (PW * CC)   // 448 = 7 waves
#define IOU_THRF 0.4f

// floor division (Python // semantics) for possibly-negative numerators
__device__ __forceinline__ int fdiv(int a, int b) {
    int q = a / b, r = a % b;
    return (r != 0 && ((r < 0) != (b < 0))) ? q - 1 : q;
}

__device__ __forceinline__ void fix_span(int& lo, int& hi, int p, int s) {
    int pad = p - (hi - lo);
    bool fmin = lo < fdiv(pad, 2);
    bool fmax = (s - hi) < fdiv(1 + pad, 2);
    bool sym = (pad > 0) && !(fmin || fmax);
    int lo2 = sym ? lo - fdiv(pad, 2) : lo;
    int hi2 = sym ? hi + fdiv(1 + pad, 2) : hi;
    if ((pad > 0) && fmin) { lo2 = 0; hi2 = p; }
    if ((pad > 0) && fmax) { lo2 = s - p; hi2 = s; }
    lo = lo2; hi = hi2;
}

// One block per (b, region n, pool-row i). Each block redundantly computes its
// batch's NMS via a 160x160 suppression bitmask (one barrier), then every
// thread scans the masks in registers (exact sequential-scan semantics),
// selects box n, clips it, and pools its (pool-col, channel) output.
__global__ __launch_bounds__(NTHREADS)
void fused_roipool(const float* __restrict__ feat, const float* __restrict__ roi,
                   float* __restrict__ out) {
    const int blk = blockIdx.x;
    const int i = blk % PH;
    const int n = (blk / PH) % NREG;
    const int b = blk / (PH * NREG);
    const int tid = threadIdx.x;

    __shared__ float sx[RR], sy[RR], sw[RR], sh[RR], sarea[RR];
    __shared__ unsigned long long sup[RR][3];

    // ---- load boxes for batch b ----
    const float* rb = roi + (size_t)b * RR * 4;
    for (int t = tid; t < RR; t += NTHREADS) {
        float x = rb[t * 4 + 0], y = rb[t * 4 + 1];
        float w = rb[t * 4 + 2], h = rb[t * 4 + 3];
        sx[t] = x; sy[t] = y; sw[t] = w; sh[t] = h;
        sarea[t] = __fmul_rn(w, h);
    }
    __syncthreads();

    // ---- suppression bitmask: sup[t] bit j set iff j>t and iou(t,j)>thr ----
    for (int item = tid; item < RR * 3; item += NTHREADS) {
        const int t = item / 3;
        const int w = item % 3;
        const int jlo = max(t + 1, w * 64);
        const int jhi = min(RR, w * 64 + 64);
        const float xi = sx[t], yi = sy[t], ai = sarea[t];
        const float x1i = __fadd_rn(xi, sw[t]);
        const float y1i = __fadd_rn(yi, sh[t]);
        unsigned long long bits = 0ull;
        for (int j = jlo; j < jhi; ++j) {
            float xa = fmaxf(xi, sx[j]);
            float ya = fmaxf(yi, sy[j]);
            float xb = fminf(x1i, __fadd_rn(sx[j], sw[j]));
            float yb = fminf(y1i, __fadd_rn(sy[j], sh[j]));
            float iw = fmaxf(__fsub_rn(xb, xa), 0.0f);
            float ih = fmaxf(__fsub_rn(yb, ya), 0.0f);
            float inter = __fmul_rn(iw, ih);
            float denom = __fsub_rn(__fadd_rn(ai, sarea[j]), inter);
            if (__fdiv_rn(inter, denom) > IOU_THRF) bits |= 1ull << (j - w * 64);
        }
        sup[t][w] = bits;
    }
    __syncthreads();

    // ---- sequential keep-scan over bitmasks (redundant per thread) ----
    // sup[t] has only bits j>t, so word0 is zero for t>=64, word1 zero for t>=128.
    unsigned long long k0 = ~0ull, k1 = ~0ull, k2 = (1ull << 32) - 1;
    for (int t = 0; t < 64; ++t) {
        unsigned long long m = 0ull - ((k0 >> t) & 1ull);
        k0 &= ~(sup[t][0] & m);
        k1 &= ~(sup[t][1] & m);
        k2 &= ~(sup[t][2] & m);
    }
    for (int t = 64; t < 128; ++t) {
        unsigned long long m = 0ull - ((k1 >> (t - 64)) & 1ull);
        k1 &= ~(sup[t][1] & m);
        k2 &= ~(sup[t][2] & m);
    }
    for (int t = 128; t < RR - 1; ++t) {
        unsigned long long m = 0ull - ((k2 >> (t - 128)) & 1ull);
        k2 &= ~(sup[t][2] & m);
    }

    // ---- select the n-th kept box (pad: box RR-1) ----
    int src = RR - 1;
    {
        int target = n;
        unsigned long long words[3] = {k0, k1, k2};
        #pragma unroll
        for (int w = 0; w < 3; ++w) {
            int pc = __popcll(words[w]);
            if (target < pc) {
                unsigned long long x = words[w];
                for (int q = 0; q < target; ++q) x &= x - 1;
                src = w * 64 + (__ffsll((long long)x) - 1);
                break;
            }
            target -= pc;
        }
    }

    // ---- clip (exact _clip_rois / _fix_span port) ----
    const float fx = sx[src], fy = sy[src], fw = sw[src], fh = sh[src];
    int x0 = max(0, (int)fx);
    int y0 = max(0, (int)fy);
    int x1 = min(WW, (int)__fadd_rn(fx, fw));
    int y1 = min(HH, (int)__fadd_rn(fy, fh));
    fix_span(x0, x1, PW, WW);
    fix_span(y0, y1, PH, HH);
    const int bw = x1 - x0, bh = y1 - y0;

    // ---- pool: this block's pool-row i; thread = (pool-col jj, channel c) ----
    const int jj = tid / CC;   // 0..6
    const int c  = tid % CC;   // 0..63
    const int hs = bh / PH, wss = bw / PW;
    const int r0 = y0 + i * hs;
    const int r1 = (i == PH - 1) ? (y0 + bh) : (r0 + hs);
    const int c0 = x0 + jj * wss;
    const int c1 = (jj == PW - 1) ? (x0 + bw) : (c0 + wss);

    const float* fb = feat + (size_t)b * HH * WW * CC;
    float v = -INFINITY;
    for (int r = r0; r < r1; ++r) {
        const float* row = fb + ((size_t)r * WW) * CC + c;
        for (int col = c0; col < c1; ++col) {
            v = fmaxf(v, row[(size_t)col * CC]);
        }
    }
    out[((((size_t)b * NREG + n) * PH + i) * PW + jj) * CC + c] = v;
}

extern "C" void kernel_launch(void* const* d_in, const int* in_sizes, int n_in,
                              void* d_out, int out_size, void* d_ws, size_t ws_size,
                              hipStream_t stream) {
    const float* features = (const float*)d_in[0];
    const float* roi      = (const float*)d_in[1];
    float* out = (float*)d_out;

    fused_roipool<<<BB * NREG * PH, NTHREADS, 0, stream>>>(features, roi, out);
}

// Round 3
// 42.024 us; speedup vs baseline: 1.4159x; 1.4159x over previous
//
#include <hip/hip_runtime.h>

#define BB 4
#define RR 160
#define HH 128
#define WW 128
#define CC 64
#define NREG 32
#define PH 7
#define PW 7
#define IOU_THRF 0.4f

// floor division (Python // semantics) for possibly-negative numerators
__device__ __forceinline__ int fdiv(int a, int b) {
    int q = a / b, r = a % b;
    return (r != 0 && ((r < 0) != (b < 0))) ? q - 1 : q;
}

__device__ __forceinline__ void fix_span(int& lo, int& hi, int p, int s) {
    int pad = p - (hi - lo);
    bool fmin = lo < fdiv(pad, 2);
    bool fmax = (s - hi) < fdiv(1 + pad, 2);
    bool sym = (pad > 0) && !(fmin || fmax);
    int lo2 = sym ? lo - fdiv(pad, 2) : lo;
    int hi2 = sym ? hi + fdiv(1 + pad, 2) : hi;
    if ((pad > 0) && fmin) { lo2 = 0; hi2 = p; }
    if ((pad > 0) && fmax) { lo2 = s - p; hi2 = s; }
    lo = lo2; hi = hi2;
}

// One block per batch. Bitmask NMS (one barrier), register keep-scan,
// select first 32 kept (pad with box RR-1), clip, write int boxes to ws.
__global__ __launch_bounds__(512)
void nms_clip_kernel(const float* __restrict__ roi, int* __restrict__ boxes_out) {
    const int b = blockIdx.x;
    const int tid = threadIdx.x;

    __shared__ float sx[RR], sy[RR], sw[RR], sh[RR], sarea[RR];
    __shared__ unsigned long long sup[RR][3];

    const float* rb = roi + (size_t)b * RR * 4;
    for (int t = tid; t < RR; t += 512) {
        float x = rb[t * 4 + 0], y = rb[t * 4 + 1];
        float w = rb[t * 4 + 2], h = rb[t * 4 + 3];
        sx[t] = x; sy[t] = y; sw[t] = w; sh[t] = h;
        sarea[t] = __fmul_rn(w, h);
    }
    __syncthreads();

    // suppression bitmask: sup[t] bit j set iff j>t and iou(t,j) > thr
    if (tid < RR * 3) {
        const int t = tid / 3;
        const int w = tid % 3;
        const int jlo = max(t + 1, w * 64);
        const int jhi = min(RR, w * 64 + 64);
        const float xi = sx[t], yi = sy[t], ai = sarea[t];
        const float x1i = __fadd_rn(xi, sw[t]);
        const float y1i = __fadd_rn(yi, sh[t]);
        unsigned long long bits = 0ull;
        for (int j = jlo; j < jhi; ++j) {
            float xa = fmaxf(xi, sx[j]);
            float ya = fmaxf(yi, sy[j]);
            float xb = fminf(x1i, __fadd_rn(sx[j], sw[j]));
            float yb = fminf(y1i, __fadd_rn(sy[j], sh[j]));
            float iw = fmaxf(__fsub_rn(xb, xa), 0.0f);
            float ih = fmaxf(__fsub_rn(yb, ya), 0.0f);
            float inter = __fmul_rn(iw, ih);
            float denom = __fsub_rn(__fadd_rn(ai, sarea[j]), inter);
            if (__fdiv_rn(inter, denom) > IOU_THRF) bits |= 1ull << (j - w * 64);
        }
        sup[t][w] = bits;
    }
    __syncthreads();

    if (tid >= NREG) return;

    // sequential keep-scan over bitmasks (exact lax.scan semantics);
    // redundant across the 32 surviving threads — negligible.
    unsigned long long k0 = ~0ull, k1 = ~0ull, k2 = (1ull << 32) - 1;
    for (int t = 0; t < 64; ++t) {
        unsigned long long m = 0ull - ((k0 >> t) & 1ull);
        k0 &= ~(sup[t][0] & m);
        k1 &= ~(sup[t][1] & m);
        k2 &= ~(sup[t][2] & m);
    }
    for (int t = 64; t < 128; ++t) {
        unsigned long long m = 0ull - ((k1 >> (t - 64)) & 1ull);
        k1 &= ~(sup[t][1] & m);
        k2 &= ~(sup[t][2] & m);
    }
    for (int t = 128; t < RR - 1; ++t) {
        unsigned long long m = 0ull - ((k2 >> (t - 128)) & 1ull);
        k2 &= ~(sup[t][2] & m);
    }

    // select the tid-th kept box (pad: box RR-1)
    int src = RR - 1;
    {
        int target = tid;
        unsigned long long words[3] = {k0, k1, k2};
        #pragma unroll
        for (int w = 0; w < 3; ++w) {
            int pc = __popcll(words[w]);
            if (target < pc) {
                unsigned long long x = words[w];
                for (int q = 0; q < target; ++q) x &= x - 1;
                src = w * 64 + (__ffsll((long long)x) - 1);
                break;
            }
            target -= pc;
        }
    }

    const float fx = sx[src], fy = sy[src], fw = sw[src], fh = sh[src];
    int x0 = max(0, (int)fx);
    int y0 = max(0, (int)fy);
    int x1 = min(WW, (int)__fadd_rn(fx, fw));
    int y1 = min(HH, (int)__fadd_rn(fy, fh));
    fix_span(x0, x1, PW, WW);
    fix_span(y0, y1, PH, HH);
    int* o = boxes_out + ((size_t)b * NREG + tid) * 4;
    o[0] = x0; o[1] = y0; o[2] = x1 - x0; o[3] = y1 - y0;
}

// One block per (b, region, pool-row i); thread = (pool-col jj, channel c).
// Each wave = one jj (c0/c1 wave-uniform); 256B coalesced loads.
__global__ __launch_bounds__(PW * CC)
void pool_kernel(const float* __restrict__ feat, const int* __restrict__ boxes,
                 float* __restrict__ out) {
    const int blk = blockIdx.x;
    const int i = blk % PH;
    const int n = (blk / PH) % NREG;
    const int b = blk / (PH * NREG);
    const int tid = threadIdx.x;
    const int jj = tid / CC;   // 0..6 (wave-uniform)
    const int c  = tid % CC;   // 0..63

    const int* bx = boxes + ((size_t)b * NREG + n) * 4;
    const int x0 = bx[0], y0 = bx[1], w = bx[2], h = bx[3];
    const int hs = h / PH, wss = w / PW;

    const int r0 = y0 + i * hs;
    const int r1 = (i == PH - 1) ? (y0 + h) : (r0 + hs);
    const int c0 = x0 + jj * wss;
    const int c1 = (jj == PW - 1) ? (x0 + w) : (c0 + wss);

    const float* fb = feat + (size_t)b * HH * WW * CC;
    float v = -INFINITY;
    for (int r = r0; r < r1; ++r) {
        const float* row = fb + ((size_t)r * WW) * CC + c;
        for (int col = c0; col < c1; ++col) {
            v = fmaxf(v, row[(size_t)col * CC]);
        }
    }
    out[((((size_t)b * NREG + n) * PH + i) * PW + jj) * CC + c] = v;
}

extern "C" void kernel_launch(void* const* d_in, const int* in_sizes, int n_in,
                              void* d_out, int out_size, void* d_ws, size_t ws_size,
                              hipStream_t stream) {
    const float* features = (const float*)d_in[0];
    const float* roi      = (const float*)d_in[1];
    float* out = (float*)d_out;
    int* boxes = (int*)d_ws;   // BB*NREG*4 ints = 2 KB

    nms_clip_kernel<<<BB, 512, 0, stream>>>(roi, boxes);
    pool_kernel<<<BB * NREG * PH, PW * CC, 0, stream>>>(features, boxes, out);
}

// Round 4
// 31.687 us; speedup vs baseline: 1.8777x; 1.3262x over previous
//
#include <hip/hip_runtime.h>

#define BB 4
#define RR 160
#define HH 128
#define WW 128
#define CC 64
#define NREG 32
#define PH 7
#define PW 7
#define IOU_THRF 0.4f

// floor division (Python // semantics) for possibly-negative numerators
__device__ __forceinline__ int fdiv(int a, int b) {
    int q = a / b, r = a % b;
    return (r != 0 && ((r < 0) != (b < 0))) ? q - 1 : q;
}

__device__ __forceinline__ void fix_span(int& lo, int& hi, int p, int s) {
    int pad = p - (hi - lo);
    bool fmin = lo < fdiv(pad, 2);
    bool fmax = (s - hi) < fdiv(1 + pad, 2);
    bool sym = (pad > 0) && !(fmin || fmax);
    int lo2 = sym ? lo - fdiv(pad, 2) : lo;
    int hi2 = sym ? hi + fdiv(1 + pad, 2) : hi;
    if ((pad > 0) && fmin) { lo2 = 0; hi2 = p; }
    if ((pad > 0) && fmax) { lo2 = s - p; hi2 = s; }
    lo = lo2; hi = hi2;
}

// One block per batch. Bitmask NMS (one barrier), fully-unrolled register
// keep-scan (static addresses -> LDS reads pipeline), select first 32 kept
// (pad with box RR-1), clip, write int boxes to ws.
__global__ __launch_bounds__(512)
void nms_clip_kernel(const float* __restrict__ roi, int* __restrict__ boxes_out) {
    const int b = blockIdx.x;
    const int tid = threadIdx.x;

    __shared__ float sx[RR], sy[RR], sw[RR], sh[RR], sarea[RR];
    __shared__ unsigned long long sup[RR][3];

    const float* rb = roi + (size_t)b * RR * 4;
    for (int t = tid; t < RR; t += 512) {
        float x = rb[t * 4 + 0], y = rb[t * 4 + 1];
        float w = rb[t * 4 + 2], h = rb[t * 4 + 3];
        sx[t] = x; sy[t] = y; sw[t] = w; sh[t] = h;
        sarea[t] = __fmul_rn(w, h);
    }
    __syncthreads();

    // suppression bitmask: sup[t] bit j set iff j>t and iou(t,j) > thr
    if (tid < RR * 3) {
        const int t = tid / 3;
        const int w = tid % 3;
        const int jlo = max(t + 1, w * 64);
        const int jhi = min(RR, w * 64 + 64);
        const float xi = sx[t], yi = sy[t], ai = sarea[t];
        const float x1i = __fadd_rn(xi, sw[t]);
        const float y1i = __fadd_rn(yi, sh[t]);
        unsigned long long bits = 0ull;
        for (int j = jlo; j < jhi; ++j) {
            float xa = fmaxf(xi, sx[j]);
            float ya = fmaxf(yi, sy[j]);
            float xb = fminf(x1i, __fadd_rn(sx[j], sw[j]));
            float yb = fminf(y1i, __fadd_rn(sy[j], sh[j]));
            float iw = fmaxf(__fsub_rn(xb, xa), 0.0f);
            float ih = fmaxf(__fsub_rn(yb, ya), 0.0f);
            float inter = __fmul_rn(iw, ih);
            float denom = __fsub_rn(__fadd_rn(ai, sarea[j]), inter);
            if (__fdiv_rn(inter, denom) > IOU_THRF) bits |= 1ull << (j - w * 64);
        }
        sup[t][w] = bits;
    }
    __syncthreads();

    if (tid >= NREG) return;

    // sequential keep-scan over bitmasks (exact lax.scan semantics).
    // Static trip counts + full unroll -> LDS reads scheduled ahead.
    unsigned long long k0 = ~0ull, k1 = ~0ull, k2 = (1ull << 32) - 1;
    #pragma unroll
    for (int t = 0; t < 64; ++t) {
        unsigned long long m = 0ull - ((k0 >> t) & 1ull);
        k0 &= ~(sup[t][0] & m);
        k1 &= ~(sup[t][1] & m);
        k2 &= ~(sup[t][2] & m);
    }
    #pragma unroll
    for (int t = 64; t < 128; ++t) {
        unsigned long long m = 0ull - ((k1 >> (t - 64)) & 1ull);
        k1 &= ~(sup[t][1] & m);
        k2 &= ~(sup[t][2] & m);
    }
    #pragma unroll
    for (int t = 128; t < RR - 1; ++t) {
        unsigned long long m = 0ull - ((k2 >> (t - 128)) & 1ull);
        k2 &= ~(sup[t][2] & m);
    }

    // select the tid-th kept box (pad: box RR-1)
    int src = RR - 1;
    {
        int target = tid;
        unsigned long long words[3] = {k0, k1, k2};
        #pragma unroll
        for (int w = 0; w < 3; ++w) {
            int pc = __popcll(words[w]);
            if (target < pc) {
                unsigned long long x = words[w];
                for (int q = 0; q < target; ++q) x &= x - 1;
                src = w * 64 + (__ffsll((long long)x) - 1);
                break;
            }
            target -= pc;
        }
    }

    const float fx = sx[src], fy = sy[src], fw = sw[src], fh = sh[src];
    int x0 = max(0, (int)fx);
    int y0 = max(0, (int)fy);
    int x1 = min(WW, (int)__fadd_rn(fx, fw));
    int y1 = min(HH, (int)__fadd_rn(fy, fh));
    fix_span(x0, x1, PW, WW);
    fix_span(y0, y1, PH, HH);
    int* o = boxes_out + ((size_t)b * NREG + tid) * 4;
    o[0] = x0; o[1] = y0; o[2] = x1 - x0; o[3] = y1 - y0;
}

// One block per (b, region, pool-row i); one wave per pool-col jj.
// Lane = (pixel-group poff 0..3, channel-quad cq 0..15): each wave-load is
// float4 x 64 lanes = 1024B = 4 consecutive pixels x 64 channels, coalesced.
// Tail pixels clamp to c1-1 (duplicate max is harmless). Final 4-way
// cross-lane max via __shfl_xor(16/32); lanes poff==0 store float4.
__global__ __launch_bounds__(PW * CC)
void pool_kernel(const float* __restrict__ feat, const int* __restrict__ boxes,
                 float* __restrict__ out) {
    const int blk = blockIdx.x;
    const int i = blk % PH;
    const int n = (blk / PH) % NREG;
    const int b = blk / (PH * NREG);
    const int wave = threadIdx.x >> 6;   // jj, 0..6 (wave-uniform)
    const int lane = threadIdx.x & 63;
    const int poff = lane >> 4;          // 0..3  pixel offset within group
    const int cq   = lane & 15;          // 0..15 channel quad

    const int* bx = boxes + ((size_t)b * NREG + n) * 4;
    const int x0 = bx[0], y0 = bx[1], w = bx[2], h = bx[3];
    const int hs = h / PH, wss = w / PW;

    const int r0 = y0 + i * hs;
    const int r1 = (i == PH - 1) ? (y0 + h) : (r0 + hs);
    const int c0 = x0 + wave * wss;
    const int c1 = (wave == PW - 1) ? (x0 + w) : (c0 + wss);

    const float* fb = feat + (size_t)b * HH * WW * CC;
    float4 v = make_float4(-INFINITY, -INFINITY, -INFINITY, -INFINITY);
    for (int r = r0; r < r1; ++r) {
        const float* rowp = fb + (size_t)(r * WW) * CC;
        for (int base = c0; base < c1; base += 4) {
            int px = base + poff;
            px = px < c1 ? px : c1 - 1;
            const float4 t = *reinterpret_cast<const float4*>(rowp + (size_t)px * CC + cq * 4);
            v.x = fmaxf(v.x, t.x);
            v.y = fmaxf(v.y, t.y);
            v.z = fmaxf(v.z, t.z);
            v.w = fmaxf(v.w, t.w);
        }
    }
    // reduce over the 4 pixel-groups: lanes {cq, cq+16, cq+32, cq+48}
    v.x = fmaxf(v.x, __shfl_xor(v.x, 16));
    v.y = fmaxf(v.y, __shfl_xor(v.y, 16));
    v.z = fmaxf(v.z, __shfl_xor(v.z, 16));
    v.w = fmaxf(v.w, __shfl_xor(v.w, 16));
    v.x = fmaxf(v.x, __shfl_xor(v.x, 32));
    v.y = fmaxf(v.y, __shfl_xor(v.y, 32));
    v.z = fmaxf(v.z, __shfl_xor(v.z, 32));
    v.w = fmaxf(v.w, __shfl_xor(v.w, 32));

    if (poff == 0) {
        float4* o = reinterpret_cast<float4*>(
            out + ((((size_t)b * NREG + n) * PH + i) * PW + wave) * CC) + cq;
        *o = v;
    }
}

extern "C" void kernel_launch(void* const* d_in, const int* in_sizes, int n_in,
                              void* d_out, int out_size, void* d_ws, size_t ws_size,
                              hipStream_t stream) {
    const float* features = (const float*)d_in[0];
    const float* roi      = (const float*)d_in[1];
    float* out = (float*)d_out;
    int* boxes = (int*)d_ws;   // BB*NREG*4 ints = 2 KB

    nms_clip_kernel<<<BB, 512, 0, stream>>>(roi, boxes);
    pool_kernel<<<BB * NREG * PH, PW * CC, 0, stream>>>(features, boxes, out);
}

// Round 5
// 30.963 us; speedup vs baseline: 1.9216x; 1.0234x over previous
//
#include <hip/hip_runtime.h>

#define BB 4
#define RR 160
#define HH 128
#define WW 128
#define CC 64
#define NREG 32
#define PH 7
#define PW 7
#define IOU_THRF 0.4f

// floor division (Python // semantics) for possibly-negative numerators
__device__ __forceinline__ int fdiv(int a, int b) {
    int q = a / b, r = a % b;
    return (r != 0 && ((r < 0) != (b < 0))) ? q - 1 : q;
}

__device__ __forceinline__ void fix_span(int& lo, int& hi, int p, int s) {
    int pad = p - (hi - lo);
    bool fmin = lo < fdiv(pad, 2);
    bool fmax = (s - hi) < fdiv(1 + pad, 2);
    bool sym = (pad > 0) && !(fmin || fmax);
    int lo2 = sym ? lo - fdiv(pad, 2) : lo;
    int hi2 = sym ? hi + fdiv(1 + pad, 2) : hi;
    if ((pad > 0) && fmin) { lo2 = 0; hi2 = p; }
    if ((pad > 0) && fmax) { lo2 = s - p; hi2 = s; }
    lo = lo2; hi = hi2;
}

// One block per batch. Bitmask NMS (one barrier), register keep-scan with
// BOUNDED unroll (8): pipelines LDS reads without spill-scale live ranges.
__global__ __launch_bounds__(512)
void nms_clip_kernel(const float* __restrict__ roi, int* __restrict__ boxes_out) {
    const int b = blockIdx.x;
    const int tid = threadIdx.x;

    __shared__ float sx[RR], sy[RR], sw[RR], sh[RR], sarea[RR];
    __shared__ unsigned long long sup[RR][3];

    const float* rb = roi + (size_t)b * RR * 4;
    for (int t = tid; t < RR; t += 512) {
        float x = rb[t * 4 + 0], y = rb[t * 4 + 1];
        float w = rb[t * 4 + 2], h = rb[t * 4 + 3];
        sx[t] = x; sy[t] = y; sw[t] = w; sh[t] = h;
        sarea[t] = __fmul_rn(w, h);
    }
    __syncthreads();

    // suppression bitmask: sup[t] bit j set iff j>t and iou(t,j) > thr
    if (tid < RR * 3) {
        const int t = tid / 3;
        const int w = tid % 3;
        const int jlo = max(t + 1, w * 64);
        const int jhi = min(RR, w * 64 + 64);
        const float xi = sx[t], yi = sy[t], ai = sarea[t];
        const float x1i = __fadd_rn(xi, sw[t]);
        const float y1i = __fadd_rn(yi, sh[t]);
        unsigned long long bits = 0ull;
        for (int j = jlo; j < jhi; ++j) {
            float xa = fmaxf(xi, sx[j]);
            float ya = fmaxf(yi, sy[j]);
            float xb = fminf(x1i, __fadd_rn(sx[j], sw[j]));
            float yb = fminf(y1i, __fadd_rn(sy[j], sh[j]));
            float iw = fmaxf(__fsub_rn(xb, xa), 0.0f);
            float ih = fmaxf(__fsub_rn(yb, ya), 0.0f);
            float inter = __fmul_rn(iw, ih);
            float denom = __fsub_rn(__fadd_rn(ai, sarea[j]), inter);
            if (__fdiv_rn(inter, denom) > IOU_THRF) bits |= 1ull << (j - w * 64);
        }
        sup[t][w] = bits;
    }
    __syncthreads();

    if (tid >= NREG) return;

    // sequential keep-scan over bitmasks (exact lax.scan semantics)
    unsigned long long k0 = ~0ull, k1 = ~0ull, k2 = (1ull << 32) - 1;
    #pragma unroll 8
    for (int t = 0; t < 64; ++t) {
        unsigned long long m = 0ull - ((k0 >> t) & 1ull);
        k0 &= ~(sup[t][0] & m);
        k1 &= ~(sup[t][1] & m);
        k2 &= ~(sup[t][2] & m);
    }
    #pragma unroll 8
    for (int t = 64; t < 128; ++t) {
        unsigned long long m = 0ull - ((k1 >> (t - 64)) & 1ull);
        k1 &= ~(sup[t][1] & m);
        k2 &= ~(sup[t][2] & m);
    }
    #pragma unroll 8
    for (int t = 128; t < RR - 1; ++t) {
        unsigned long long m = 0ull - ((k2 >> (t - 128)) & 1ull);
        k2 &= ~(sup[t][2] & m);
    }

    // select the tid-th kept box (pad: box RR-1)
    int src = RR - 1;
    {
        int target = tid;
        unsigned long long words[3] = {k0, k1, k2};
        #pragma unroll
        for (int w = 0; w < 3; ++w) {
            int pc = __popcll(words[w]);
            if (target < pc) {
                unsigned long long x = words[w];
                for (int q = 0; q < target; ++q) x &= x - 1;
                src = w * 64 + (__ffsll((long long)x) - 1);
                break;
            }
            target -= pc;
        }
    }

    const float fx = sx[src], fy = sy[src], fw = sw[src], fh = sh[src];
    int x0 = max(0, (int)fx);
    int y0 = max(0, (int)fy);
    int x1 = min(WW, (int)__fadd_rn(fx, fw));
    int y1 = min(HH, (int)__fadd_rn(fy, fh));
    fix_span(x0, x1, PW, WW);
    fix_span(y0, y1, PH, HH);
    int* o = boxes_out + ((size_t)b * NREG + tid) * 4;
    o[0] = x0; o[1] = y0; o[2] = x1 - x0; o[3] = y1 - y0;
}

// One block per (b, region, pool-row i); one wave per pool-col jj.
// XCD-affinity remap: HW assigns block g -> XCD g%8; we decode so all 7
// pool-rows of one (b,n) region land on the SAME XCD (L2 reuse of the
// ~50-70KB region instead of 7x L3-mediated refetch).
// Lane = (pixel-group poff 0..3, channel-quad cq 0..15): each wave-load is
// float4 x 64 lanes = 1024B, fully coalesced. Tail pixels clamp to c1-1
// (duplicate max harmless). 4-way cross-lane max via __shfl_xor(16/32).
__global__ __launch_bounds__(PW * CC)
void pool_kernel(const float* __restrict__ feat, const int* __restrict__ boxes,
                 float* __restrict__ out) {
    // bijective decode: xcd x = g%8 owns (b,n) pairs [x*16, x*16+16)
    const int g = blockIdx.x;
    const int x = g & 7;          // XCD slot
    const int q = g >> 3;         // 0..111
    const int pair = x * 16 + q / 7;   // 0..127
    const int i = q % 7;               // pool row
    const int n = pair & (NREG - 1);
    const int b = pair >> 5;

    const int wave = threadIdx.x >> 6;   // jj, 0..6 (wave-uniform)
    const int lane = threadIdx.x & 63;
    const int poff = lane >> 4;          // 0..3  pixel offset within group
    const int cq   = lane & 15;          // 0..15 channel quad

    const int* bx = boxes + ((size_t)b * NREG + n) * 4;
    const int x0 = bx[0], y0 = bx[1], w = bx[2], h = bx[3];
    const int hs = h / PH, wss = w / PW;

    const int r0 = y0 + i * hs;
    const int r1 = (i == PH - 1) ? (y0 + h) : (r0 + hs);
    const int c0 = x0 + wave * wss;
    const int c1 = (wave == PW - 1) ? (x0 + w) : (c0 + wss);

    const float* fb = feat + (size_t)b * HH * WW * CC;
    float4 v = make_float4(-INFINITY, -INFINITY, -INFINITY, -INFINITY);
    #pragma unroll 2
    for (int r = r0; r < r1; ++r) {
        const float* rowp = fb + (size_t)(r * WW) * CC;
        for (int base = c0; base < c1; base += 4) {
            int px = base + poff;
            px = px < c1 ? px : c1 - 1;
            const float4 t = *reinterpret_cast<const float4*>(rowp + (size_t)px * CC + cq * 4);
            v.x = fmaxf(v.x, t.x);
            v.y = fmaxf(v.y, t.y);
            v.z = fmaxf(v.z, t.z);
            v.w = fmaxf(v.w, t.w);
        }
    }
    // reduce over the 4 pixel-groups: lanes {cq, cq+16, cq+32, cq+48}
    v.x = fmaxf(v.x, __shfl_xor(v.x, 16));
    v.y = fmaxf(v.y, __shfl_xor(v.y, 16));
    v.z = fmaxf(v.z, __shfl_xor(v.z, 16));
    v.w = fmaxf(v.w, __shfl_xor(v.w, 16));
    v.x = fmaxf(v.x, __shfl_xor(v.x, 32));
    v.y = fmaxf(v.y, __shfl_xor(v.y, 32));
    v.z = fmaxf(v.z, __shfl_xor(v.z, 32));
    v.w = fmaxf(v.w, __shfl_xor(v.w, 32));

    if (poff == 0) {
        float4* o = reinterpret_cast<float4*>(
            out + ((((size_t)b * NREG + n) * PH + i) * PW + wave) * CC) + cq;
        *o = v;
    }
}

extern "C" void kernel_launch(void* const* d_in, const int* in_sizes, int n_in,
                              void* d_out, int out_size, void* d_ws, size_t ws_size,
                              hipStream_t stream) {
    const float* features = (const float*)d_in[0];
    const float* roi      = (const float*)d_in[1];
    float* out = (float*)d_out;
    int* boxes = (int*)d_ws;   // BB*NREG*4 ints = 2 KB

    nms_clip_kernel<<<BB, 512, 0, stream>>>(roi, boxes);
    pool_kernel<<<BB * NREG * PH, PW * CC, 0, stream>>>(features, boxes, out);
}